// Round 1
// baseline (63.298 us; speedup 1.0000x reference)
//
#include <hip/hip_runtime.h>

// HiPoNet collapse: P = 0.5*colnorm(Wm) + 0.5*I is column-stochastic
// (1^T P = 1^T), so mean-pool(P^t X) == mean-pool(X) for every t.
// Output[b, w, k, j] = mean_n(pc[b,n,j]) * alphas[w,j], tiled k=0..4.

#define NPTS   2048
#define DIM    32
#define BATCH  4
#define NW     4
#define NFEAT  5           // [X, PX, P^2X, P^4X, P^8X] -> all identical after pooling
#define BLOCKS_PER_B 16
#define OUT_TOTAL (BATCH * NW * NFEAT * DIM)   // 2560

__global__ __launch_bounds__(256) void pc_mean_partial(const float* __restrict__ pc,
                                                       float* __restrict__ acc) {
    // grid = BATCH * BLOCKS_PER_B blocks, 256 threads each.
    const int b    = blockIdx.x / BLOCKS_PER_B;
    const int blk  = blockIdx.x % BLOCKS_PER_B;
    const int rows = NPTS / BLOCKS_PER_B;      // 128 rows per block
    const int row0 = blk * rows;
    const int t  = threadIdx.x;
    const int j  = t & 31;   // feature column
    const int rg = t >> 5;   // row group 0..7

    const float* base = pc + (size_t)b * NPTS * DIM + (size_t)row0 * DIM;
    float s = 0.f;
    // thread t reads addresses base + t + 256*i  -> perfectly coalesced
    for (int r = rg; r < rows; r += 8)
        s += base[r * DIM + j];

    __shared__ float sm[8][32];
    sm[rg][j] = s;
    __syncthreads();
    if (t < 32) {
        float tot = 0.f;
#pragma unroll
        for (int g = 0; g < 8; ++g) tot += sm[g][t];
        atomicAdd(&acc[b * DIM + t], tot);
    }
}

__global__ __launch_bounds__(256) void finalize(const float* __restrict__ acc,
                                                const float* __restrict__ alphas,
                                                float* __restrict__ out) {
    const int idx = blockIdx.x * blockDim.x + threadIdx.x;
    if (idx >= OUT_TOTAL) return;
    const int j = idx & 31;
    const int w = (idx / (DIM * NFEAT)) % NW;
    const int b = idx / (DIM * NFEAT * NW);
    out[idx] = (acc[b * DIM + j] * (1.0f / NPTS)) * alphas[w * DIM + j];
}

extern "C" void kernel_launch(void* const* d_in, const int* in_sizes, int n_in,
                              void* d_out, int out_size, void* d_ws, size_t ws_size,
                              hipStream_t stream) {
    const float* pc     = (const float*)d_in[0];   // [4, 2048, 32] fp32
    // d_in[1] = sigma (scalar) — unused: output is sigma-invariant (see header)
    const float* alphas = (const float*)d_in[2];   // [4, 32] fp32
    float*       out    = (float*)d_out;           // [4, 640] fp32
    float*       acc    = (float*)d_ws;            // [4, 32] partial sums

    hipMemsetAsync(acc, 0, BATCH * DIM * sizeof(float), stream);
    pc_mean_partial<<<BATCH * BLOCKS_PER_B, 256, 0, stream>>>(pc, acc);
    finalize<<<(OUT_TOTAL + 255) / 256, 256, 0, stream>>>(acc, alphas, out);
}

// Round 2
// 59.663 us; speedup vs baseline: 1.0609x; 1.0609x over previous
//
#include <hip/hip_runtime.h>

// HiPoNet collapse: P = 0.5*colnorm(Wm) + 0.5*I is column-stochastic
// (1^T P = 1^T), so mean-pool(P^t X) == mean-pool(X) for every t.
// Output[b, w, k*32+j] = mean_n(pc[b,n,j]) * alphas[w,j] for k=0..4.
//
// Single kernel, one block per batch, no workspace (avoids any dependency
// on the harness's 256 MB d_ws poison fill), no atomics, no memset.

#define NPTS   2048
#define DIM    32
#define BATCH  4
#define NW     4
#define NFEAT  5
#define PER_B  (NPTS * DIM)          // 65536 floats = 16384 float4
#define OUT_PER_B (NW * NFEAT * DIM) // 640

__global__ __launch_bounds__(1024) void hiponet_fused(const float* __restrict__ pc,
                                                      const float* __restrict__ alphas,
                                                      float* __restrict__ out) {
    const int b = blockIdx.x;
    const int t = threadIdx.x;

    // Coalesced float4 read of this batch's [2048 x 32] slice.
    // float4 index f covers columns 4*(f&7)..4*(f&7)+3, so component c of
    // thread t's accumulator is the partial sum of column 4*(t&7)+c.
    const float4* base = (const float4*)(pc + (size_t)b * PER_B);
    float4 s = make_float4(0.f, 0.f, 0.f, 0.f);
#pragma unroll
    for (int i = 0; i < 16; ++i) {
        float4 v = base[t + i * 1024];
        s.x += v.x; s.y += v.y; s.z += v.z; s.w += v.w;
    }

    __shared__ float4 sm[1024];
    sm[t] = s;
    __syncthreads();

    // Tree-reduce; strides stay multiples of 8 so column groups align.
#pragma unroll
    for (int str = 512; str >= 8; str >>= 1) {
        if (t < str) {
            float4 a = sm[t], c = sm[t + str];
            a.x += c.x; a.y += c.y; a.z += c.z; a.w += c.w;
            sm[t] = a;
        }
        __syncthreads();
    }
    // sm[0..7] as flat floats = column sums for columns 0..31.

    __shared__ float mean[DIM];
    if (t < DIM) mean[t] = ((const float*)sm)[t] * (1.0f / NPTS);
    __syncthreads();

    if (t < OUT_PER_B) {
        const int j = t & 31;
        const int w = t / (NFEAT * DIM);
        out[(size_t)b * OUT_PER_B + t] = mean[j] * alphas[w * DIM + j];
    }
}

extern "C" void kernel_launch(void* const* d_in, const int* in_sizes, int n_in,
                              void* d_out, int out_size, void* d_ws, size_t ws_size,
                              hipStream_t stream) {
    const float* pc     = (const float*)d_in[0];   // [4, 2048, 32] fp32
    // d_in[1] = sigma — unused: pooled output is sigma/threshold-invariant
    const float* alphas = (const float*)d_in[2];   // [4, 32] fp32
    float*       out    = (float*)d_out;           // [4, 640] fp32

    hiponet_fused<<<BATCH, 1024, 0, stream>>>(pc, alphas, out);
}

// Round 3
// 58.812 us; speedup vs baseline: 1.0763x; 1.0145x over previous
//
#include <hip/hip_runtime.h>

// HiPoNet collapse: P = 0.5*colnorm(Wm) + 0.5*I is column-stochastic
// (1^T P = 1^T), so mean-pool(P^t X) == mean-pool(X) for every t.
// Output[b, w, k*32+j] = mean_n(pc[b,n,j]) * alphas[w,j] for k=0..4.
//
// Two tiny kernels: 64-block parallel partial-sum (reads 1 MB at aggregate
// BW instead of 4 CUs' worth), then a one-block combine+outer-product.
// d_ws holds plain-store partials (no init needed, no atomics); the
// harness's 256 MB ws poison fill (~40 us) runs regardless of ws use.

#define NPTS   2048
#define DIM    32
#define BATCH  4
#define NW     4
#define NFEAT  5
#define BLK_PER_B 16
#define NBLK   (BATCH * BLK_PER_B)       // 64
#define ROWS   (NPTS / BLK_PER_B)        // 128 rows per block
#define OUT_PER_B (NW * NFEAT * DIM)     // 640
#define OUT_TOTAL (BATCH * OUT_PER_B)    // 2560

__global__ __launch_bounds__(256) void partial_sums(const float* __restrict__ pc,
                                                    float* __restrict__ ws) {
    const int b   = blockIdx.x / BLK_PER_B;
    const int blk = blockIdx.x % BLK_PER_B;
    const int t   = threadIdx.x;

    // This block's slice: 128 rows x 32 cols = 1024 float4, coalesced.
    const float4* base = (const float4*)(pc + (size_t)b * NPTS * DIM
                                            + (size_t)blk * ROWS * DIM);
    float4 s = make_float4(0.f, 0.f, 0.f, 0.f);
#pragma unroll
    for (int i = 0; i < 4; ++i) {
        float4 v = base[t + i * 256];   // (t+256i)&7 == t&7: fixed column group
        s.x += v.x; s.y += v.y; s.z += v.z; s.w += v.w;
    }

    __shared__ float4 sm[256];
    sm[t] = s;
    __syncthreads();
#pragma unroll
    for (int str = 128; str >= 8; str >>= 1) {   // strides stay multiples of 8
        if (t < str) {
            float4 a = sm[t], c = sm[t + str];
            a.x += c.x; a.y += c.y; a.z += c.z; a.w += c.w;
            sm[t] = a;
        }
        __syncthreads();
    }
    // sm[0..7] flat = 32 column sums for this block's 128 rows.
    if (t < DIM)
        ws[blockIdx.x * DIM + t] = ((const float*)sm)[t];
}

__global__ __launch_bounds__(256) void combine(const float* __restrict__ ws,
                                               const float* __restrict__ alphas,
                                               float* __restrict__ out) {
    const int t = threadIdx.x;
    __shared__ float mean[BATCH * DIM];   // 128

    if (t < BATCH * DIM) {
        const int b = t >> 5, j = t & 31;
        float s = 0.f;
#pragma unroll
        for (int k = 0; k < BLK_PER_B; ++k)
            s += ws[(b * BLK_PER_B + k) * DIM + j];
        mean[t] = s * (1.0f / NPTS);
    }
    __syncthreads();

#pragma unroll
    for (int i = 0; i < OUT_TOTAL / 256; ++i) {   // 10 outputs per thread
        const int idx = t + i * 256;
        const int b = idx / OUT_PER_B;
        const int r = idx % OUT_PER_B;
        const int j = r & 31;
        const int w = r / (NFEAT * DIM);
        out[idx] = mean[b * DIM + j] * alphas[w * DIM + j];
    }
}

extern "C" void kernel_launch(void* const* d_in, const int* in_sizes, int n_in,
                              void* d_out, int out_size, void* d_ws, size_t ws_size,
                              hipStream_t stream) {
    const float* pc     = (const float*)d_in[0];   // [4, 2048, 32] fp32
    // d_in[1] = sigma — unused: pooled output is sigma/threshold-invariant
    const float* alphas = (const float*)d_in[2];   // [4, 32] fp32
    float*       out    = (float*)d_out;           // [4, 640] fp32
    float*       ws     = (float*)d_ws;            // 64*32 partial sums

    partial_sums<<<NBLK, 256, 0, stream>>>(pc, ws);
    combine<<<1, 256, 0, stream>>>(ws, alphas, out);
}